// Round 9
// baseline (72.558 us; speedup 1.0000x reference)
//
#include <hip/hip_runtime.h>

// KDA state update:
//   coef[e] = beta * (v[e] - sum_d alpha[d]*k[d]*S[d][e])
//   S_new[d][e] = alpha[d]*S[d][e] + k[d]*coef[e]
//   o[e]    = sum_d q[d] * S_new[d][e]
//
// B=64, H=32, DK=DV=128 -> 2048 heads. ROUND-5 GEOMETRY (the 44.5us champion,
// empirically the only one that keeps FETCH at 67.7MB: one head per 128-thread
// block, thread e owns COLUMN e, all d-reductions thread-local, one barrier).
// Single change vs round 5: no s_col[128] register array -- pass 2 explicitly
// re-reads S (L2/L3-hit, proven by round 5's unchanged FETCH despite a logical
// double read). This cuts VGPRs 84 -> ~32, doubling resident waves.
// NT stores keep Sout out of the caches.

#define DK 128
#define DV 128

__global__ __launch_bounds__(128) void kda_update_kernel(
    const float* __restrict__ S,
    const float* __restrict__ k,
    const float* __restrict__ v,
    const float* __restrict__ q,
    const float* __restrict__ alpha,
    const float* __restrict__ beta,
    float* __restrict__ Sout,
    float* __restrict__ o)
{
    const int bh = blockIdx.x;
    const int e  = threadIdx.x;        // column index 0..127

    __shared__ float sak[DK];          // alpha[d]*k[d]
    __shared__ float sa[DK];
    __shared__ float sk[DK];
    __shared__ float sq[DK];

    const size_t hoff = (size_t)bh * DK * DV;
    const float* __restrict__ Sbh = S + hoff;

    // Stage per-head vectors into LDS (one element per thread).
    {
        const float kk = k[(size_t)bh * DK + e];
        const float aa = alpha[(size_t)bh * DK + e];
        sk[e]  = kk;
        sa[e]  = aa;
        sak[e] = kk * aa;
        sq[e]  = q[(size_t)bh * DK + e];
    }
    __syncthreads();

    // ---- Pass 1: kts = sum_d ak[d]*S[d][e], thread-local (no s_col array).
    float kts = 0.f;
    #pragma unroll
    for (int d = 0; d < DK; ++d) {
        kts += sak[d] * Sbh[(size_t)d * DV + e];
    }

    const float coef = beta[bh] * (v[(size_t)bh * DV + e] - kts);

    // ---- Pass 2: re-read column (cache-hit), S_new, nt-store, accumulate o.
    float oacc = 0.f;
    float* __restrict__ Sobh = Sout + hoff;
    #pragma unroll
    for (int d = 0; d < DK; ++d) {
        const float sn = sa[d] * Sbh[(size_t)d * DV + e] + sk[d] * coef;
        __builtin_nontemporal_store(sn, Sobh + (size_t)d * DV + e);
        oacc += sq[d] * sn;
    }

    o[(size_t)bh * DV + e] = oacc;
}

extern "C" void kernel_launch(void* const* d_in, const int* in_sizes, int n_in,
                              void* d_out, int out_size, void* d_ws, size_t ws_size,
                              hipStream_t stream) {
    const float* S     = (const float*)d_in[0];
    const float* k     = (const float*)d_in[1];
    const float* v     = (const float*)d_in[2];
    const float* q     = (const float*)d_in[3];
    const float* alpha = (const float*)d_in[4];
    const float* beta  = (const float*)d_in[5];

    const int BH = in_sizes[5];  // beta has B*H elements -> 2048 heads

    float* Sout = (float*)d_out;
    float* o    = Sout + (size_t)BH * DK * DV;

    kda_update_kernel<<<dim3(BH), dim3(128), 0, stream>>>(S, k, v, q, alpha, beta, Sout, o);
}

// Round 10
// 56.152 us; speedup vs baseline: 1.2922x; 1.2922x over previous
//
#include <hip/hip_runtime.h>

// KDA state update:
//   coef[e] = beta * (v[e] - sum_d alpha[d]*k[d]*S[d][e])
//   S_new[d][e] = alpha[d]*S[d][e] + k[d]*coef[e]
//   o[e]    = sum_d q[d] * S_new[d][e]
//
// B=64, H=32, DK=DV=128 -> 2048 heads. ROUND-5 CHAMPION STRUCTURE (44.5us):
// one head per 128-thread block, thread e owns COLUMN e of S held in a
// register array (SINGLE read of S from the memory system -- empirically the
// property that keeps FETCH at 67.7MB vs 133MB for any double-read variant;
// rounds 6-9 all proved re-reads miss L3 at replay-scale reuse distance).
//
// Single change vs round 5: Sout stores use inline-asm global_store_dword
// with sc0+sc1+nt (full no-allocate/streaming through L2+MALL) instead of
// __builtin_nontemporal_store (nt only). Goal: stop the 132MB write stream
// from evicting S out of the 256MB Infinity Cache, making S fully
// L3-resident across graph replays (FETCH 67.7MB -> ~0-30MB).

#define DK 128
#define DV 128

__global__ __launch_bounds__(128) void kda_update_kernel(
    const float* __restrict__ S,
    const float* __restrict__ k,
    const float* __restrict__ v,
    const float* __restrict__ q,
    const float* __restrict__ alpha,
    const float* __restrict__ beta,
    float* __restrict__ Sout,
    float* __restrict__ o)
{
    const int bh = blockIdx.x;
    const int e  = threadIdx.x;        // column index 0..127

    __shared__ float sak[DK];          // alpha[d]*k[d]
    __shared__ float sa[DK];
    __shared__ float sk[DK];
    __shared__ float sq[DK];

    const size_t hoff = (size_t)bh * DK * DV;
    const float* __restrict__ Sbh = S + hoff;

    // Stage per-head vectors into LDS (one element per thread).
    {
        const float kk = k[(size_t)bh * DK + e];
        const float aa = alpha[(size_t)bh * DK + e];
        sk[e]  = kk;
        sa[e]  = aa;
        sak[e] = kk * aa;
        sq[e]  = q[(size_t)bh * DK + e];
    }
    __syncthreads();

    // ---- Pass 1: load column e of S into registers (single memory-system
    //              read), accumulate kts = sum_d ak[d]*S[d][e] thread-locally.
    float s_col[DK];
    float kts = 0.f;
    #pragma unroll
    for (int d = 0; d < DK; ++d) {
        s_col[d] = Sbh[(size_t)d * DV + e];
        kts += sak[d] * s_col[d];
    }

    const float coef = beta[bh] * (v[(size_t)bh * DV + e] - kts);

    // ---- Pass 2: S_new column from registers; streaming store (sc0 sc1 nt);
    //              accumulate o[e].
    float oacc = 0.f;
    float* __restrict__ Sobh = Sout + hoff;
    #pragma unroll
    for (int d = 0; d < DK; ++d) {
        const float sn = sa[d] * s_col[d] + sk[d] * coef;
        float* p = Sobh + (size_t)d * DV + e;
        asm volatile("global_store_dword %0, %1, off sc0 sc1 nt"
                     :: "v"(p), "v"(sn));
        oacc += sq[d] * sn;
    }

    o[(size_t)bh * DV + e] = oacc;

    // Ensure asm streaming stores are drained before wave end.
    asm volatile("s_waitcnt vmcnt(0)" ::: "memory");
}

extern "C" void kernel_launch(void* const* d_in, const int* in_sizes, int n_in,
                              void* d_out, int out_size, void* d_ws, size_t ws_size,
                              hipStream_t stream) {
    const float* S     = (const float*)d_in[0];
    const float* k     = (const float*)d_in[1];
    const float* v     = (const float*)d_in[2];
    const float* q     = (const float*)d_in[3];
    const float* alpha = (const float*)d_in[4];
    const float* beta  = (const float*)d_in[5];

    const int BH = in_sizes[5];  // beta has B*H elements -> 2048 heads

    float* Sout = (float*)d_out;
    float* o    = Sout + (size_t)BH * DK * DV;

    kda_update_kernel<<<dim3(BH), dim3(128), 0, stream>>>(S, k, v, q, alpha, beta, Sout, o);
}

// Round 11
// 47.043 us; speedup vs baseline: 1.5424x; 1.1936x over previous
//
#include <hip/hip_runtime.h>

// KDA state update:
//   coef[e]     = beta * (v[e] - sum_d alpha[d]*k[d]*S[d][e])
//   S_new[d][e] = alpha[d]*S[d][e] + k[d]*coef[e]
//   o[e]        = sum_d q[d]*S_new[d][e]
//               = sum_d q[d]*alpha[d]*S[d][e]  +  (sum_d q[d]*k[d]) * coef[e]
//
// B=64, H=32, DK=DV=128 -> 2048 heads. Single-read structure (empirically
// required: any second pass over S misses L3 at replay reuse distance and
// doubles HBM fetch, rounds 6-9). One head per 256-thread block; thread owns
// a 16-row x 4-col float4 register tile of S. The o-reduction is REFORMULATED
// into pass 1 (qas accumulated alongside kts; qk via wave shuffles at stage
// time), so pass 2 is pure compute+nt-store: no trailing FMAs, no second LDS
// reduce, one fewer barrier. NT stores keep the write stream from polluting
// more of L3 than necessary.

#define DK 128
#define DV 128

typedef float v4f __attribute__((ext_vector_type(4)));
typedef float v2f __attribute__((ext_vector_type(2)));

__global__ __launch_bounds__(256) void kda_update_kernel(
    const float* __restrict__ S,
    const float* __restrict__ k,
    const float* __restrict__ v,
    const float* __restrict__ q,
    const float* __restrict__ alpha,
    const float* __restrict__ beta,
    float* __restrict__ Sout,
    float* __restrict__ o)
{
    const int bh   = blockIdx.x;
    const int tid  = threadIdx.x;
    const int col4 = (tid & 31) * 4;   // this thread's 4 columns
    const int rgrp = tid >> 5;         // 0..7 : rows rgrp*16 .. rgrp*16+15
    const int d0   = rgrp * 16;

    __shared__ float sa[DK];
    __shared__ float sk[DK];
    __shared__ float sak[DK];          // alpha*k
    __shared__ float sqa[DK];          // q*alpha
    __shared__ float scoef[DV];
    __shared__ v2f   red[8][DV];       // {kts_part, qas_part}
    __shared__ float sqk[2];           // per-half-wave partials of sum q*k

    const size_t hoff = (size_t)bh * DK * DV;
    const float* __restrict__ Sbh = S + hoff;

    // ---- Stage per-head vectors; compute qk = sum_d q[d]*k[d] via shuffles.
    if (tid < DK) {
        const float kk = k[(size_t)bh * DK + tid];
        const float aa = alpha[(size_t)bh * DK + tid];
        const float qq = q[(size_t)bh * DK + tid];
        sk[tid]  = kk;
        sa[tid]  = aa;
        sak[tid] = kk * aa;
        sqa[tid] = qq * aa;
        float p = qq * kk;
        p += __shfl_xor(p, 32);
        p += __shfl_xor(p, 16);
        p += __shfl_xor(p, 8);
        p += __shfl_xor(p, 4);
        p += __shfl_xor(p, 2);
        p += __shfl_xor(p, 1);
        if ((tid & 63) == 0) sqk[tid >> 6] = p;   // tid 0 and 64
    }
    __syncthreads();

    // ---- Pass 1: load S tile into registers (single memory-system read);
    //      accumulate kts (for coef) AND qas (for o) per column.
    float s_reg[16][4];
    v4f kts = {0.f, 0.f, 0.f, 0.f};
    v4f qas = {0.f, 0.f, 0.f, 0.f};

    #pragma unroll
    for (int i = 0; i < 16; ++i) {
        const int d = d0 + i;
        const v4f sv = *reinterpret_cast<const v4f*>(Sbh + (size_t)d * DV + col4);
        s_reg[i][0] = sv.x; s_reg[i][1] = sv.y; s_reg[i][2] = sv.z; s_reg[i][3] = sv.w;
        kts += sak[d] * sv;
        qas += sqa[d] * sv;
    }

    red[rgrp][col4 + 0] = (v2f){kts.x, qas.x};
    red[rgrp][col4 + 1] = (v2f){kts.y, qas.y};
    red[rgrp][col4 + 2] = (v2f){kts.z, qas.z};
    red[rgrp][col4 + 3] = (v2f){kts.w, qas.w};
    __syncthreads();

    // ---- Reduce across the 8 row-groups; coef + o (o needs no pass 2!).
    if (tid < DV) {
        v2f acc = {0.f, 0.f};
        #pragma unroll
        for (int g = 0; g < 8; ++g) acc += red[g][tid];
        const float coef = beta[bh] * (v[(size_t)bh * DV + tid] - acc.x);
        scoef[tid] = coef;
        const float qk = sqk[0] + sqk[1];
        o[(size_t)bh * DV + tid] = acc.y + qk * coef;
    }
    __syncthreads();

    const float c0 = scoef[col4 + 0];
    const float c1 = scoef[col4 + 1];
    const float c2 = scoef[col4 + 2];
    const float c3 = scoef[col4 + 3];

    // ---- Pass 2: pure compute + nt store from registers.
    float* __restrict__ Sobh = Sout + hoff;
    #pragma unroll
    for (int i = 0; i < 16; ++i) {
        const int d = d0 + i;
        const float a  = sa[d];
        const float kk = sk[d];
        v4f ov;
        ov.x = a * s_reg[i][0] + kk * c0;
        ov.y = a * s_reg[i][1] + kk * c1;
        ov.z = a * s_reg[i][2] + kk * c2;
        ov.w = a * s_reg[i][3] + kk * c3;
        __builtin_nontemporal_store(ov, reinterpret_cast<v4f*>(Sobh + (size_t)d * DV + col4));
    }
}

extern "C" void kernel_launch(void* const* d_in, const int* in_sizes, int n_in,
                              void* d_out, int out_size, void* d_ws, size_t ws_size,
                              hipStream_t stream) {
    const float* S     = (const float*)d_in[0];
    const float* k     = (const float*)d_in[1];
    const float* v     = (const float*)d_in[2];
    const float* q     = (const float*)d_in[3];
    const float* alpha = (const float*)d_in[4];
    const float* beta  = (const float*)d_in[5];

    const int BH = in_sizes[5];  // beta has B*H elements -> 2048 heads

    float* Sout = (float*)d_out;
    float* o    = Sout + (size_t)BH * DK * DV;

    kda_update_kernel<<<dim3(BH), dim3(256), 0, stream>>>(S, k, v, q, alpha, beta, Sout, o);
}